// Round 18
// baseline (978.235 us; speedup 1.0000x reference)
//
#include <hip/hip_runtime.h>
#include <hip/hip_bf16.h>
#include <hip/hip_fp16.h>
#include <cmath>

// Problem constants
#define BATCH   8
#define D_MODEL 512
#define N2      32
#define LSEQ    4096
#define NLAYERS 4
#define CIN     3
#define NBDL    (16777216u)   // BATCH*D_MODEL*LSEQ
#define PN      (D_MODEL * N2)            // params per layer
#define WN      (2 * D_MODEL * D_MODEL)   // weights per layer

typedef __attribute__((ext_vector_type(8))) short short8;   // 8 bf16 (4 VGPRs)
typedef __attribute__((ext_vector_type(4))) float floatx4;  // MFMA accum

// ---------------------------------------------------------------------------
// Static device scratch. Every buffer fully overwritten before read, each call.
// Per layer: ssd writes y (bf16) into g_yb -> glu reads y from g_yb (in-LDS
// transpose staging) and writes z (fp16) into g_yt -> ln reads z from g_yt.
// ---------------------------------------------------------------------------
__device__ float   g_h[NBDL];                                  // 64 MB h (B,D,L) fp32
__device__ __align__(16) __hip_bfloat16 g_yb[NBDL];            // 32 MB y bf16 (B,D,L)
__device__ __align__(16) __hip_bfloat16 g_yt[NBDL];            // 32 MB z fp16 (B,D,L)
__device__ __align__(16) __hip_bfloat16 g_wb[NLAYERS * WN];    // 8 MB W bf16, all layers
__device__ __align__(16) __hip_bfloat16 g_G[(size_t)NLAYERS * 512 * 6 * 4096]; // 96 MB SSD mats
__device__ __align__(16) float g_posT[D_MODEL * LSEQ];         // 8 MB pos^T fp32
__device__ float4  g_p[NLAYERS * PN];                          // SSM params, all layers
__device__ float   g_hm[BATCH * D_MODEL];                      // mean over L
__device__ int     g_flag;                                     // 1=fp32, 0=bf16, 2=fp16

__device__ __forceinline__ float bfbits2f(unsigned short u) {
    union { unsigned int i; float f; } x; x.i = ((unsigned int)u) << 16; return x.f;
}
__device__ __forceinline__ float halfbits2f(unsigned short u) {
    __half h; *(unsigned short*)&h = u; return __half2float(h);
}
__device__ __forceinline__ float ldin(const void* p, size_t i, int m) {
    if (m == 1) return ((const float*)p)[i];
    unsigned short u = ((const unsigned short*)p)[i];
    if (m == 0) return bfbits2f(u);
    return halfbits2f(u);
}
__device__ __forceinline__ unsigned int pk2(float a, float b) {
    __hip_bfloat16 ha = __float2bfloat16(a), hb = __float2bfloat16(b);
    unsigned short ua, ub;
    __builtin_memcpy(&ua, &ha, 2); __builtin_memcpy(&ub, &hb, 2);
    return (unsigned int)ua | ((unsigned int)ub << 16);
}
// split a pair of fp32 into packed bf16 hi-words and bf16 lo-residual words
__device__ __forceinline__ void split2(float a, float b, unsigned int& hp, unsigned int& lp) {
    __hip_bfloat16 ah = __float2bfloat16(a), bh = __float2bfloat16(b);
    unsigned short ua, ub;
    __builtin_memcpy(&ua, &ah, 2); __builtin_memcpy(&ub, &bh, 2);
    hp = (unsigned int)ua | ((unsigned int)ub << 16);
    lp = pk2(a - __bfloat162float(ah), b - __bfloat162float(bh));
}
__device__ __forceinline__ unsigned short bf16u(float a) {
    __hip_bfloat16 h = __float2bfloat16(a);
    unsigned short u; __builtin_memcpy(&u, &h, 2); return u;
}
// complex integer power by binary exponentiation (exact-ish fp32, e in [0,64])
__device__ __forceinline__ float2 cpow_(float br, float bi, int e) {
    float rr = 1.f, ri = 0.f;
    while (e) {
        if (e & 1) { float t = rr * br - ri * bi; ri = rr * bi + ri * br; rr = t; }
        float t = br * br - bi * bi; bi = 2.f * br * bi; br = t;
        e >>= 1;
    }
    return make_float2(rr, ri);
}

// Branchless erf-based exact GELU (A&S 7.1.26, |err| < 1.5e-7)
__device__ __forceinline__ float fast_gelu(float x) {
    float z = x * 0.70710678118654752f;
    float a = fabsf(z);
    float t = __builtin_amdgcn_rcpf(fmaf(0.3275911f, a, 1.0f));
    float p = t * fmaf(t, fmaf(t, fmaf(t, fmaf(t, 1.061405429f, -1.453152027f),
                                       1.421413741f), -0.284496736f), 0.254829592f);
    float e = __expf(-a * a);
    float er = fmaf(-p, e, 1.0f);            // erf(|z|)
    er = copysignf(er, z);
    float hx = 0.5f * x;
    return fmaf(hx, er, hx);
}

// ---------------------------------------------------------------------------
// 0) dtype probe on A_imag (= pi*arange(32) broadcast; elt[1]=pi, elt[3]=3pi)
// ---------------------------------------------------------------------------
__global__ void detect_kernel(const unsigned short* a) {
    if (threadIdx.x == 0) {
        unsigned short h1 = a[1], h3 = a[3];
        int f;
        if (h1 == 0x0000 && h3 == 0x4049) f = 1;   // fp32 layout
        else if (h1 == 0x4049)            f = 0;   // native bf16
        else if (h1 == 0x4248)            f = 2;   // native fp16
        else                              f = 1;
        g_flag = f;
    }
}

__global__ __launch_bounds__(256) void sentinel_kernel(float* out, float v) {
    out[blockIdx.x * 256 + threadIdx.x] = v;
}

// ---------------------------------------------------------------------------
// 0b) pos transpose: g_posT[o][l] = pos[l][o] (fp32 exact). 64x64 LDS tiles.
// ---------------------------------------------------------------------------
__global__ __launch_bounds__(256) void pos_t_kernel(const void* pos) {
    __shared__ float T[64][65];
    const int m = g_flag;
    int tid = threadIdx.x;
    int bid = blockIdx.x;                // 0..511 = ltile*8 + otile
    int l0 = (bid >> 3) * 64;
    int o0 = (bid & 7) * 64;
    int a  = tid & 63;
    int g4 = tid >> 6;                   // 0..3
#pragma unroll
    for (int p = 0; p < 16; p++) {
        int ll = g4 * 16 + p;
        T[a][ll] = ldin(pos, (size_t)(l0 + ll) * D_MODEL + o0 + a, m);  // lanes: o-fast (coalesced)
    }
    __syncthreads();
#pragma unroll
    for (int p = 0; p < 16; p++) {
        int oo = g4 * 16 + p;
        g_posT[(size_t)(o0 + oo) * LSEQ + l0 + a] = T[oo][a];           // lanes: l-fast (coalesced)
    }
}

// ---------------------------------------------------------------------------
// 1) Input projection v3 — thread per (o,l), b looped in registers.
// ---------------------------------------------------------------------------
__global__ __launch_bounds__(256) void proj_kernel(const void* x, const void* Wproj,
                                                   const void* bproj) {
    const int m = g_flag;
    unsigned idx = blockIdx.x * 256 + threadIdx.x;   // over D_MODEL*LSEQ
    int l = idx & (LSEQ - 1);
    int o = idx >> 12;                               // 0..511
    float acc0 = ldin(bproj, o, m) + g_posT[(size_t)o * LSEQ + l];
    float w0 = ldin(Wproj, o * CIN + 0, m);
    float w1 = ldin(Wproj, o * CIN + 1, m);
    float w2 = ldin(Wproj, o * CIN + 2, m);
#pragma unroll
    for (int b = 0; b < BATCH; b++) {
        float acc = acc0;
        acc = fmaf(w0, ldin(x, (size_t)(b * CIN + 0) * LSEQ + l, m), acc);
        acc = fmaf(w1, ldin(x, (size_t)(b * CIN + 1) * LSEQ + l, m), acc);
        acc = fmaf(w2, ldin(x, (size_t)(b * CIN + 2) * LSEQ + l, m), acc);
        g_h[(size_t)(b * D_MODEL + o) * LSEQ + l] = acc;
    }
}

// ---------------------------------------------------------------------------
// 2) SSM param prep — ALL layers in one launch.
// ---------------------------------------------------------------------------
__global__ __launch_bounds__(256) void prep_kernel(const void* log_dt, const void* log_A_real,
                                                   const void* A_imag, const void* C_re,
                                                   const void* C_im) {
    const int m = g_flag;
    int idx = blockIdx.x * 256 + threadIdx.x;        // over NLAYERS*PN
    int layer = idx >> 14;                           // PN = 16384
    int i = idx & (PN - 1);
    int hh = i >> 5;
    size_t oH = (size_t)layer * D_MODEL;
    size_t oN = (size_t)layer * PN;
    float dt  = expf(ldin(log_dt, oH + hh, m));
    float a   = expf(ldin(log_A_real, oN + i, m));
    float bi  = ldin(A_imag, oN + i, m);
    float dre = -a * dt, dim = bi * dt;
    float er  = expf(dre);
    float wr  = er * cosf(dim);
    float wi  = er * sinf(dim);
    float Er  = wr - 1.0f, Ei = wi;
    float inv = 1.0f / (a * a + bi * bi);
    float Tr = (-Er * a + Ei * bi) * inv;
    float Ti = -(Er * bi + Ei * a) * inv;
    float cr = ldin(C_re, oN + i, m), ci = ldin(C_im, oN + i, m);
    float c2r = 2.0f * (cr * Tr - ci * Ti);
    float c2i = 2.0f * (cr * Ti + ci * Tr);
    g_p[idx] = make_float4(wr, wi, c2r, c2i);
}

// ---------------------------------------------------------------------------
// 2b) Pack Wout to bf16 — ALL layers in one launch.
// ---------------------------------------------------------------------------
__global__ __launch_bounds__(256) void pack_w_kernel(const void* Wout) {
    int idx = blockIdx.x * 256 + threadIdx.x;        // over NLAYERS*WN
    g_wb[idx] = __float2bfloat16(ldin(Wout, idx, g_flag));
}

// ---------------------------------------------------------------------------
// 2c) SSD matrix precompute v2 — geometric stepping.
// ---------------------------------------------------------------------------
__global__ __launch_bounds__(256) void gmat_kernel() {
    __shared__ float4 psh[32];
    __shared__ unsigned short Khi[64], Klo[64];
    __shared__ __align__(16) unsigned short sC[2][64][72];   // 18.4 KB C staging
    float (*Kpart)[64] = (float(*)[64])&sC[0][0][0];         // 8 KB alias (pre-C)
    int tid = threadIdx.x;
    int bid = blockIdx.x;                   // layer*512 + h
    int layer = bid >> 9, h = bid & 511;
    if (tid < 32) psh[tid] = g_p[(size_t)layer * PN + h * N2 + tid];
    __syncthreads();
    // K partials: thread (n, dseg), tid<128: w^d stepped along d
    if (tid < 128) {
        int n = tid >> 2, dseg = (tid & 3) * 16;
        float4 pv = psh[n];
        float wr = pv.x, wi = pv.y;
        float2 wd = cpow_(wr, wi, dseg);
#pragma unroll
        for (int i = 0; i < 16; i++) {
            Kpart[n][dseg + i] = pv.z * wd.x - pv.w * wd.y;
            float t2 = wd.x * wr - wd.y * wi;
            wd.y = wd.x * wi + wd.y * wr; wd.x = t2;
        }
    }
    __syncthreads();
    if (tid < 64) {
        float acc = 0.f;
#pragma unroll
        for (int n = 0; n < 32; n++) acc += Kpart[n][tid];
        unsigned short khu = bf16u(acc);
        Khi[tid] = khu;
        Klo[tid] = bf16u(acc - bfbits2f(khu));
    }
    __syncthreads();                        // Kpart dead; sC reusable below
    unsigned short* Gu = (unsigned short*)(g_G + (size_t)bid * 6 * 4096);
    int t = tid >> 2, jseg = (tid & 3) * 16;
    // ---- M rows (gather from Khi/Klo, coalesced 16B stores) ----
    {
        unsigned int mh[8], ml[8];
#pragma unroll
        for (int i2 = 0; i2 < 8; i2++) {
            int d0 = t - jseg - 2 * i2;
            int d1 = d0 - 1;
            unsigned int h0 = (d0 >= 0) ? (unsigned int)Khi[d0] : 0u;
            unsigned int h1 = (d1 >= 0) ? (unsigned int)Khi[d1] : 0u;
            unsigned int l0v = (d0 >= 0) ? (unsigned int)Klo[d0] : 0u;
            unsigned int l1v = (d1 >= 0) ? (unsigned int)Klo[d1] : 0u;
            mh[i2] = h0 | (h1 << 16);
            ml[i2] = l0v | (l1v << 16);
        }
        uint4 v;
        v.x = mh[0]; v.y = mh[1]; v.z = mh[2]; v.w = mh[3];
        *(uint4*)&Gu[t * 64 + jseg] = v;
        v.x = mh[4]; v.y = mh[5]; v.z = mh[6]; v.w = mh[7];
        *(uint4*)&Gu[t * 64 + jseg + 8] = v;
        v.x = ml[0]; v.y = ml[1]; v.z = ml[2]; v.w = ml[3];
        *(uint4*)&Gu[4096 + t * 64 + jseg] = v;
        v.x = ml[4]; v.y = ml[5]; v.z = ml[6]; v.w = ml[7];
        *(uint4*)&Gu[4096 + t * 64 + jseg + 8] = v;
    }
    // ---- A rows: w^{63-j}, stepped ascending e = descending j ----
    {
        int n = t >> 1;
        float4 pv = psh[n];
        float wr = pv.x, wi = pv.y;
        float av[16];
        float2 wd = cpow_(wr, wi, 48 - jseg);           // e for col jseg+15
#pragma unroll
        for (int i = 15; i >= 0; i--) {
            av[i] = (t & 1) ? wd.y : wd.x;
            float t2 = wd.x * wr - wd.y * wi;
            wd.y = wd.x * wi + wd.y * wr; wd.x = t2;
        }
        unsigned int ah[8], al[8];
#pragma unroll
        for (int i2 = 0; i2 < 8; i2++)
            split2(av[2 * i2], av[2 * i2 + 1], ah[i2], al[i2]);
        uint4 v;
        v.x = ah[0]; v.y = ah[1]; v.z = ah[2]; v.w = ah[3];
        *(uint4*)&Gu[2 * 4096 + t * 64 + jseg] = v;
        v.x = ah[4]; v.y = ah[5]; v.z = ah[6]; v.w = ah[7];
        *(uint4*)&Gu[2 * 4096 + t * 64 + jseg + 8] = v;
        v.x = al[0]; v.y = al[1]; v.z = al[2]; v.w = al[3];
        *(uint4*)&Gu[3 * 4096 + t * 64 + jseg] = v;
        v.x = al[4]; v.y = al[5]; v.z = al[6]; v.w = al[7];
        *(uint4*)&Gu[3 * 4096 + t * 64 + jseg + 8] = v;
    }
    // ---- C cols: c2*w^{t+1}, stepped along t; stage in LDS ----
    {
        int j = tid >> 2, tseg = (tid & 3) * 16;
        int n = j >> 1;
        float4 pv = psh[n];
        float wr = pv.x, wi = pv.y;
        float2 wd = cpow_(wr, wi, tseg + 1);
#pragma unroll
        for (int i = 0; i < 16; i++) {
            float zr = pv.z * wd.x - pv.w * wd.y;
            float zi = pv.z * wd.y + pv.w * wd.x;
            float cv = (j & 1) ? -zi : zr;
            unsigned short chu = bf16u(cv);
            sC[0][tseg + i][j] = chu;
            sC[1][tseg + i][j] = bf16u(cv - bfbits2f(chu));
            float t2 = wd.x * wr - wd.y * wi;
            wd.y = wd.x * wi + wd.y * wr; wd.x = t2;
        }
    }
    __syncthreads();
    // coalesced copy out of the C staging
    *(uint4*)&Gu[4 * 4096 + t * 64 + jseg]     = *(uint4*)&sC[0][t][jseg];
    *(uint4*)&Gu[4 * 4096 + t * 64 + jseg + 8] = *(uint4*)&sC[0][t][jseg + 8];
    *(uint4*)&Gu[5 * 4096 + t * 64 + jseg]     = *(uint4*)&sC[1][t][jseg];
    *(uint4*)&Gu[5 * 4096 + t * 64 + jseg + 8] = *(uint4*)&sC[1][t][jseg + 8];
}

// ---------------------------------------------------------------------------
// 3) SSD kernel v5: 512 threads / 8 waves per block, same 63.5 KB LDS ->
//    still 2 blocks/CU but 16 waves/CU = 4 waves/SIMD (was 2). Wave (wr,wc)
//    owns 2 row-tiles (mi in {2wr,2wr+1}) x 16 cols (cidx = wc*16+nm).
//    Per-output MFMA sequence unchanged -> bit-identical arithmetic.
// ---------------------------------------------------------------------------
__global__ __launch_bounds__(512) void ssd_kernel(const void* Dskip, int layer) {
    __shared__ unsigned short sMhi[64][72];   // 9216 B each, 144 B row stride
    __shared__ unsigned short sMlo[64][72];
    __shared__ unsigned short sAC[64][72];    // A (hi then lo), later C (hi then lo)
    __shared__ unsigned short sUhi[64][72];
    __shared__ unsigned short sUlo[64][72];
    __shared__ float sPf[64][68];             // P fp32; later S hi/lo bf16 (17408 B)
    const int m = g_flag;
    int tid = threadIdx.x;
    int h = blockIdx.x;                       // 0..511
    const unsigned short* Gsrc = (const unsigned short*)g_G + (size_t)(layer * 512 + h) * 6 * 4096;

    int row = tid >> 3, seg = (tid & 7) * 8;  // staging: 64 rows x 8 segs (one uint4)

    // prologue: M hi/lo (once) + Ahi + u(b=0)
    {
        const unsigned short* s = Gsrc + row * 64 + seg;
        *(uint4*)&sMhi[row][seg] = *(const uint4*)(s);
        *(uint4*)&sMlo[row][seg] = *(const uint4*)(s + 4096);
        *(uint4*)&sAC[row][seg]  = *(const uint4*)(s + 2 * 4096);
    }
    {
        const float* up = g_h + (size_t)h * LSEQ + row * 64 + seg;   // b = 0
        float4 va = *(const float4*)(up);
        float4 vb = *(const float4*)(up + 4);
        uint4 H, L;
        split2(va.x, va.y, H.x, L.x);
        split2(va.z, va.w, H.y, L.y);
        split2(vb.x, vb.y, H.z, L.z);
        split2(vb.z, vb.w, H.w, L.w);
        *(uint4*)&sUhi[row][seg] = H;
        *(uint4*)&sUlo[row][seg] = L;
    }

    // hoisted scan constants (wave0 lanes) + dsk (all threads)
    float sWr = 0.f, sWi = 0.f;
    if (tid < 32) {
        float4 pv = g_p[(size_t)layer * PN + h * N2 + tid];
        float Wr = pv.x, Wi = pv.y;
#pragma unroll
        for (int s6 = 0; s6 < 6; s6++) { float t2 = Wr * Wr - Wi * Wi; Wi = 2.f * Wr * Wi; Wr = t2; }
        sWr = Wr; sWi = Wi;
    }
    float dsk = ldin(Dskip, (size_t)layer * D_MODEL + h, m);

    int lane = tid & 63, wave = tid >> 6;
    int q = lane >> 4, nm = lane & 15;
    int wr = wave >> 2, wc = wave & 3;
    int cidx = wc * 16 + nm;                                   // this lane's col (chunk)
    int mrow0 = wr * 32;                                       // this wave's first row
    floatx4 zed = {0.f, 0.f, 0.f, 0.f};

    for (int b = 0; b < 8; b++) {
        __syncthreads();                                        // B1 (staging visible)
        // T14: issue u(b+1) loads EARLY into regs; latency hides under b's work
        float4 nu0, nu1;
        if (b < 7) {
            const float* up = g_h + (size_t)((b + 1) * D_MODEL + h) * LSEQ + row * 64 + seg;
            nu0 = *(const float4*)(up);
            nu1 = *(const float4*)(up + 4);
        }
        floatx4 pacc[2] = {zed, zed};
        // GEMM2a: P += Ahi@(Uhi + Ulo)
#pragma unroll
        for (int k0 = 0; k0 < 64; k0 += 32) {
            short8 bh = *(short8*)&sUhi[cidx][k0 + q * 8];
            short8 bl = *(short8*)&sUlo[cidx][k0 + q * 8];
#pragma unroll
            for (int ml = 0; ml < 2; ml++) {
                short8 a = *(short8*)&sAC[mrow0 + ml * 16 + nm][k0 + q * 8];
                pacc[ml] = __builtin_amdgcn_mfma_f32_16x16x32_bf16(a, bh, pacc[ml], 0, 0, 0);
                pacc[ml] = __builtin_amdgcn_mfma_f32_16x16x32_bf16(a, bl, pacc[ml], 0, 0, 0);
            }
        }
        __syncthreads();                                        // B2 (Ahi reads done)
        if (tid >= 256) {   // L2: Alo (256 threads, 16 shorts each)
            int idx = tid - 256, row2 = idx >> 2, seg2 = (idx & 3) * 16;
            const unsigned short* s = Gsrc + 3 * 4096 + row2 * 64 + seg2;
            *(uint4*)&sAC[row2][seg2]     = *(const uint4*)(s);
            *(uint4*)&sAC[row2][seg2 + 8] = *(const uint4*)(s + 8);
        }
        __syncthreads();                                        // B3
        // GEMM2b: P += Alo@Uhi; store P ([col][row]) to LDS fp32
#pragma unroll
        for (int k0 = 0; k0 < 64; k0 += 32) {
            short8 bh = *(short8*)&sUhi[cidx][k0 + q * 8];
#pragma unroll
            for (int ml = 0; ml < 2; ml++) {
                short8 a = *(short8*)&sAC[mrow0 + ml * 16 + nm][k0 + q * 8];
                pacc[ml] = __builtin_amdgcn_mfma_f32_16x16x32_bf16(a, bh, pacc[ml], 0, 0, 0);
            }
        }
#pragma unroll
        for (int ml = 0; ml < 2; ml++)
            *(floatx4*)&sPf[cidx][mrow0 + ml * 16 + q * 4] = pacc[ml];
        __syncthreads();                                        // B4 (P visible)

        // inter-chunk scan (wave0 lanes 0..31), in-place S over P
        if (tid < 32) {
            int n = tid;
            float Sr = 0.f, Si = 0.f;
            for (int c = 0; c < 64; c++) {
                unsigned int* wp = (unsigned int*)&sPf[c][0];
                unsigned int pru = wp[2 * n], piu = wp[2 * n + 1];   // read P BEFORE S write
                float pr = __uint_as_float(pru), pi = __uint_as_float(piu);
                unsigned int shw, slw;
                split2(Sr, Si, shw, slw);
                wp[n]      = shw;                                    // Shi ushorts [0..63]
                wp[32 + n] = slw;                                    // Slo ushorts [64..127]
                float t2 = fmaf(sWr, Sr, fmaf(-sWi, Si, pr));
                Si = fmaf(sWr, Si, fmaf(sWi, Sr, pi));
                Sr = t2;
            }
        }
        if (tid >= 256) {   // L3: Chi (concurrent with scan; A dead after B4)
            int idx = tid - 256, row2 = idx >> 2, seg2 = (idx & 3) * 16;
            const unsigned short* s = Gsrc + 4 * 4096 + row2 * 64 + seg2;
            *(uint4*)&sAC[row2][seg2]     = *(const uint4*)(s);
            *(uint4*)&sAC[row2][seg2 + 8] = *(const uint4*)(s + 8);
        }
        __syncthreads();                                        // B5 (S + Chi ready)

        // GEMM1: Yintra = (Mhi+Mlo)@(Uhi+Ulo); GEMM3a: Ycarry = Chi@(Shi+Slo)
        floatx4 accA[2] = {zed, zed};
        floatx4 accB[2] = {zed, zed};
#pragma unroll
        for (int k0 = 0; k0 < 64; k0 += 32) {
            short8 bh = *(short8*)&sUhi[cidx][k0 + q * 8];
            short8 bl = *(short8*)&sUlo[cidx][k0 + q * 8];
            const unsigned short* srow = (const unsigned short*)&sPf[cidx][0];
            short8 sh = *(short8*)(srow + k0 + q * 8);
            short8 sl = *(short8*)(srow + 64 + k0 + q * 8);
#pragma unroll
            for (int ml = 0; ml < 2; ml++) {
                short8 amh = *(short8*)&sMhi[mrow0 + ml * 16 + nm][k0 + q * 8];
                short8 aml = *(short8*)&sMlo[mrow0 + ml * 16 + nm][k0 + q * 8];
                short8 ac  = *(short8*)&sAC [mrow0 + ml * 16 + nm][k0 + q * 8];
                accA[ml] = __builtin_amdgcn_mfma_f32_16x16x32_bf16(amh, bh, accA[ml], 0, 0, 0);
                accA[ml] = __builtin_amdgcn_mfma_f32_16x16x32_bf16(amh, bl, accA[ml], 0, 0, 0);
                accA[ml] = __builtin_amdgcn_mfma_f32_16x16x32_bf16(aml, bh, accA[ml], 0, 0, 0);
                accB[ml] = __builtin_amdgcn_mfma_f32_16x16x32_bf16(ac,  sh, accB[ml], 0, 0, 0);
                accB[ml] = __builtin_amdgcn_mfma_f32_16x16x32_bf16(ac,  sl, accB[ml], 0, 0, 0);
            }
        }
        __syncthreads();                                        // B6 (Chi reads done)
        if (tid >= 256) {   // L4: Clo
            int idx = tid - 256, row2 = idx >> 2, seg2 = (idx & 3) * 16;
            const unsigned short* s = Gsrc + 5 * 4096 + row2 * 64 + seg2;
            *(uint4*)&sAC[row2][seg2]     = *(const uint4*)(s);
            *(uint4*)&sAC[row2][seg2 + 8] = *(const uint4*)(s + 8);
        }
        __syncthreads();                                        // B7
        // GEMM3b: Ycarry += Clo@Shi
#pragma unroll
        for (int k0 = 0; k0 < 64; k0 += 32) {
            const unsigned short* srow = (const unsigned short*)&sPf[cidx][0];
            short8 sh = *(short8*)(srow + k0 + q * 8);
#pragma unroll
            for (int ml = 0; ml < 2; ml++) {
                short8 ac = *(short8*)&sAC[mrow0 + ml * 16 + nm][k0 + q * 8];
                accB[ml] = __builtin_amdgcn_mfma_f32_16x16x32_bf16(ac, sh, accB[ml], 0, 0, 0);
            }
        }

        // epilogue: y = Yintra + Ycarry + dsk*u -> gelu -> bf16 store
        __hip_bfloat16* yb = g_yb + (size_t)(b * D_MODEL + h) * LSEQ;
#pragma unroll
        for (int ml = 0; ml < 2; ml++) {
            int t0 = mrow0 + ml * 16 + q * 4;
            uint2 uh = *(uint2*)&sUhi[cidx][t0];
            uint2 ul = *(uint2*)&sUlo[cidx][t0];
            float u0 = bfbits2f((unsigned short)(uh.x & 0xFFFF)) + bfbits2f((unsigned short)(ul.x & 0xFFFF));
            float u1 = bfbits2f((unsigned short)(uh.x >> 16))    + bfbits2f((unsigned short)(ul.x >> 16));
            float u2 = bfbits2f((unsigned short)(uh.y & 0xFFFF)) + bfbits2f((unsigned short)(ul.y & 0xFFFF));
            float u3 = bfbits2f((unsigned short)(uh.y >> 16))    + bfbits2f((unsigned short)(ul.y >> 16));
            float y0 = fast_gelu(accA[ml][0] + accB[ml][0] + dsk * u0);
            float y1 = fast_gelu(accA[ml][1] + accB[ml][1] + dsk * u1);
            float y2 = fast_gelu(accA[ml][2] + accB[ml][2] + dsk * u2);
            float y3 = fast_gelu(accA[ml][3] + accB[ml][3] + dsk * u3);
            uint2 o;
            o.x = pk2(y0, y1);
            o.y = pk2(y2, y3);
            *(uint2*)&yb[cidx * 64 + t0] = o;
        }
        __syncthreads();                                        // B8 (sAC/sU reads done)
        if (b < 7) {
            // restage Ahi (L2-hot) + u(b+1) from the early-issued regs
            {
                const unsigned short* s = Gsrc + 2 * 4096 + row * 64 + seg;
                *(uint4*)&sAC[row][seg] = *(const uint4*)(s);
            }
            {
                uint4 H, L;
                split2(nu0.x, nu0.y, H.x, L.x);
                split2(nu0.z, nu0.w, H.y, L.y);
                split2(nu1.x, nu1.y, H.z, L.z);
                split2(nu1.z, nu1.w, H.w, L.w);
                *(uint4*)&sUhi[row][seg] = H;
                *(uint4*)&sUlo[row][seg] = L;
            }
        }
    }
}

// ---------------------------------------------------------------------------
// 4) MFMA GLU v7: v4 + physical row permutation phi(r) = r ^ (((r>>6)&3)<<1)
//    on the Ytd tile (staging write conflicts 4-way -> 2-way = free).
// ---------------------------------------------------------------------------
__global__ __launch_bounds__(256, 4) void glu_mfma_kernel(const void* bout, int layer) {
    __shared__ __align__(16) unsigned char smem[25600];
    unsigned short (* __restrict__ Wa)[40] = (unsigned short(*)[40])(smem);          // 2560 B
    unsigned short (* __restrict__ Wb)[40] = (unsigned short(*)[40])(smem + 2560);   // 2560 B
    unsigned int*  __restrict__ Ytd        = (unsigned int*)(smem + 5120);           // 256 rows x 20 dwords = 20480 B
    unsigned short (* __restrict__ Zs)[264] = (unsigned short(*)[264])(smem);        // 16896 B (aliases, post-loop)
    const int m = g_flag;
    int tid  = threadIdx.x;
    int wave = tid >> 6, lane = tid & 63;
    int q = lane >> 4, nm = lane & 15;
    int bid = blockIdx.x;                    // 0..2047
    int xcd = bid & 7;
    int qb  = bid >> 3;                      // 0..255
    int rt  = qb & 15;                       // 0..15  (32 o-rows) fast within XCD
    int ct  = (xcd << 4) | (qb >> 4);        // 0..127 (256 l-cols) 16 per XCD
    int col0 = ct * 256;
    int row0 = rt * 32;
    int b  = col0 >> 12;                     // single batch per block
    int l0 = col0 & (LSEQ - 1);
    const unsigned short* __restrict__ Ybb =
        (const unsigned short*)g_yb + (size_t)b * D_MODEL * LSEQ;
    const __hip_bfloat16* __restrict__ Wbase = g_wb + (size_t)layer * WN;

    floatx4 accA[2][4], accB[2][4];
    floatx4 zed = {0.f, 0.f, 0.f, 0.f};
#pragma unroll
    for (int i = 0; i < 2; i++)
#pragma unroll
        for (int j = 0; j < 4; j++) { accA[i][j] = zed; accB[i][j] = zed; }

    int sk = (tid & 3) * 8;         // 0,8,16,24 (W staging col)
    int wrow = (tid & 127) >> 2;    // 0..31 (W staging row)
    int p  = tid >> 4;              // 0..15 k-pair for y staging
    int sg = tid & 15;              // 0..15 l-segment (16 l each)
    int Xw = (sg & 3) << 2;         // write swizzle (dwords)
    int xorv = (sg >> 2) << 1;      // row permutation phi: bits 1-2 of row idx
    unsigned int rowbase = (unsigned)(sg * 16) * 20 + (unsigned)(p ^ Xw);
    int wavecol = wave * 64;

    for (int k0 = 0; k0 < D_MODEL; k0 += 32) {
        if (tid < 128)
            *(uint4*)&Wa[wrow][sk] = *(const uint4*)&Wbase[(size_t)(row0 + wrow) * D_MODEL + k0 + sk];
        else
            *(uint4*)&Wb[wrow][sk] = *(const uint4*)&Wbase[(size_t)(row0 + wrow + D_MODEL) * D_MODEL + k0 + sk];
        // y staging with in-LDS transpose: rows k0+2p, k0+2p+1, l-seg sg*16..+15
        // phi row permutation: value for local row jj stored at row (jj ^ xorv)
        {
            const unsigned short* yA = Ybb + (size_t)(k0 + 2 * p) * LSEQ + l0 + sg * 16;
            uint4 a0 = *(const uint4*)yA;
            uint4 a1 = *(const uint4*)(yA + 8);
            uint4 b0 = *(const uint4*)(yA + LSEQ);
            uint4 b1 = *(const uint4*)(yA + LSEQ + 8);
#define PKW(au, bu, jj)  { \
            Ytd[rowbase + ((jj) ^ xorv) * 20]       = ((au) & 0xFFFFu) | ((bu) << 16); \
            Ytd[rowbase + (((jj) + 1) ^ xorv) * 20] = ((au) >> 16) | ((bu) & 0xFFFF0000u); }
            PKW(a0.x, b0.x, 0)  PKW(a0.y, b0.y, 2)  PKW(a0.z, b0.z, 4)  PKW(a0.w, b0.w, 6)
            PKW(a1.x, b1.x, 8)  PKW(a1.y, b1.y, 10) PKW(a1.z, b1.z, 12) PKW(a1.w, b1.w, 14)
#undef PKW
        }
        __syncthreads();
        short8 afa[2], afb[2];
#pragma unroll
        for (int mi = 0; mi < 2; mi++) {
            afa[mi] = *(short8*)&Wa[mi * 16 + nm][q * 8];
            afb[mi] = *(short8*)&Wb[mi * 16 + nm][q * 8];
        }
#pragma unroll
        for (int ni = 0; ni < 4; ni++) {
            int r = wavecol + ni * 16 + nm;
            int pr = r ^ (((r >> 6) & 3) << 1);      // phi (uniform shift within wave)
            int Xr = ((r >> 4) & 3) << 2;
            short8 bf = *(short8*)(Ytd + pr * 20 + ((q * 4) ^ Xr));
#pragma unroll
            for (int mi = 0; mi < 2; mi++) {
                accA[mi][ni] = __builtin_amdgcn_mfma_f32_16x16x32_bf16(afa[mi], bf, accA[mi][ni], 0, 0, 0);
                accB[mi][ni] = __builtin_amdgcn_mfma_f32_16x16x32_bf16(afb[mi], bf, accB[mi][ni], 0, 0, 0);
            }
        }
        __syncthreads();
    }

    // epilogue: z -> LDS repack (fp16), then coalesced global stores to g_yt
    size_t boff = (size_t)layer * 2 * D_MODEL;
#pragma unroll
    for (int mi = 0; mi < 2; mi++) {
#pragma unroll
        for (int r = 0; r < 4; r++) {
            int lrow = mi * 16 + q * 4 + r;          // 0..31
            int o = row0 + lrow;
            float ba  = ldin(bout, boff + o, m);
            float bb2 = ldin(bout, boff + o + D_MODEL, m);
#pragma unroll
            for (int ni = 0; ni < 4; ni++) {
                int lcol = wavecol + ni * 16 + nm;
                float aa = accA[mi][ni][r] + ba;
                float bv = accB[mi][ni][r] + bb2;
                float z  = aa * __builtin_amdgcn_rcpf(1.0f + __expf(-bv));
                __half hz = __float2half(z);
                unsigned short hzb;
                __builtin_memcpy(&hzb, &hz, 2);
                Zs[lrow][lcol] = hzb;
            }
        }
    }
    __syncthreads();
    unsigned short* __restrict__ Zb =
        (unsigned short*)g_yt + (size_t)b * D_MODEL * LSEQ;
    int zrow = tid >> 3;             // 0..31
    int zcol = (tid & 7) * 32;       // 0..224 (shorts)
    size_t gbase = (size_t)(row0 + zrow) * LSEQ + l0 + zcol;
#pragma unroll
    for (int i = 0; i < 4; i++)
        *(uint4*)&Zb[gbase + i * 8] = *(uint4*)&Zs[zrow][zcol + i * 8];
}

// ---------------------------------------------------------------------------
// 5) LayerNorm over D with fused residual: h = LN(h + z), z fp16 from g_yt.
// ---------------------------------------------------------------------------
__global__ __launch_bounds__(256) void ln_kernel(const void* g, const void* bt, int layer) {
    __shared__ float s_sum[8][32];
    __shared__ float s_sq[8][32];
    __shared__ float s_mu[32], s_rs[32];
    const int m = g_flag;
    int tid = threadIdx.x;
    int l  = tid & 31;
    int dg = tid >> 5;                   // 0..7 -> d range [dg*64, dg*64+64)
    int bl = blockIdx.x;                 // 0..1023 = b*128 + ltile
    int b  = bl >> 7;
    int l0 = (bl & 127) * 32;
    size_t base = (size_t)b * D_MODEL * LSEQ + l0 + l;
    float* __restrict__ hp = g_h + base + (size_t)(dg * 64) * LSEQ;
    const unsigned short* __restrict__ zp =
        (const unsigned short*)g_yt + base + (size_t)(dg * 64) * LSEQ;
    size_t goff = (size_t)layer * D_MODEL + dg * 64;
    float varr[64];
    float sum = 0.f, sq = 0.f;
#pragma unroll
    for (int i = 0; i < 64; i++) {
        float v = hp[(size_t)i * LSEQ] + halfbits2f(zp[(size_t)i * LSEQ]);
        varr[i] = v;
        sum += v; sq += v * v;
    }
    s_sum[dg][l] = sum; s_sq[dg][l] = sq;
    __syncthreads();
    if (tid < 32) {
        float s = 0.f, qq = 0.f;
#pragma unroll
        for (int gq = 0; gq < 8; gq++) { s += s_sum[gq][tid]; qq += s_sq[gq][tid]; }
        float mu = s * (1.0f / D_MODEL);
        float var = qq * (1.0f / D_MODEL) - mu * mu;
        s_mu[tid] = mu;
        s_rs[tid] = rsqrtf(var + 1e-5f);
    }
    __syncthreads();
    float mu = s_mu[l], rs = s_rs[l];
#pragma unroll
    for (int i = 0; i < 64; i++) {
        hp[(size_t)i * LSEQ] = (varr[i] - mu) * rs * ldin(g, goff + i, m) + ldin(bt, goff + i, m);
    }
}

// ---------------------------------------------------------------------------
// 6) Mean over L: one block per (b,d)
// ---------------------------------------------------------------------------
__global__ __launch_bounds__(256) void mean_kernel() {
    int bd = blockIdx.x;
    int tid = threadIdx.x;
    const float* __restrict__ row = g_h + (size_t)bd * LSEQ;
    float s = 0.f;
    for (int l = tid; l < LSEQ; l += 256) s += row[l];
#pragma unroll
    for (int off = 32; off > 0; off >>= 1) s += __shfl_down(s, off, 64);
    __shared__ float red[4];
    if ((tid & 63) == 0) red[tid >> 6] = s;
    __syncthreads();
    if (tid == 0) g_hm[bd] = (red[0] + red[1] + red[2] + red[3]) * (1.0f / LSEQ);
}

// ---------------------------------------------------------------------------
// 7) Final stats head -> FP32 output (mu flat || log_sig flat)
// ---------------------------------------------------------------------------
__global__ __launch_bounds__(256) void stats_kernel(const void* Wst, const void* bst,
                                                    float* __restrict__ out) {
    const int m = g_flag;
    int idx = blockIdx.x * 256 + threadIdx.x;
    int b = idx >> 9, o = idx & (D_MODEL - 1);
    const float* __restrict__ hb = g_hm + b * D_MODEL;
    float acc = ldin(bst, o, m);
    for (int d = 0; d < D_MODEL; d++)
        acc = fmaf(hb[d], ldin(Wst, (size_t)o * D_MODEL + d, m), acc);
    int pos = (o < 256) ? (b * 256 + o) : (2048 + b * 256 + (o - 256));
    out[pos] = acc;
}

// ---------------------------------------------------------------------------
extern "C" void kernel_launch(void* const* d_in, const int* in_sizes, int n_in,
                              void* d_out, int out_size, void* d_ws, size_t ws_size,
                              hipStream_t stream) {
    static const int exp_sizes[16] = {98304, 1536, 512, 2097152, 2048, 65536, 65536,
                                      65536, 65536, 2048, 2097152, 4096, 2048, 2048,
                                      262144, 512};
    bool ok = (n_in == 16);
    if (ok) for (int i = 0; i < 16; i++) if (in_sizes[i] != exp_sizes[i]) { ok = false; break; }
    if (!ok) {
        sentinel_kernel<<<(out_size + 255) / 256, 256, 0, stream>>>((float*)d_out, 1000.0f);
        return;
    }
    if (out_size != 4096) {
        sentinel_kernel<<<(out_size + 255) / 256, 256, 0, stream>>>((float*)d_out, 300.0f);
        return;
    }

    const void* x          = d_in[0];
    const void* Wproj      = d_in[1];
    const void* bproj      = d_in[2];
    const void* pos        = d_in[3];
    const void* log_dt     = d_in[4];
    const void* log_A_real = d_in[5];
    const void* A_imag     = d_in[6];
    const void* C_re       = d_in[7];
    const void* C_im       = d_in[8];
    const void* Dskip      = d_in[9];
    const void* Wout       = d_in[10];
    const void* bout       = d_in[11];
    const void* ln_g       = d_in[12];
    const void* ln_b       = d_in[13];
    const void* Wstats     = d_in[14];
    const void* bstats     = d_in[15];

    detect_kernel<<<1, 64, 0, stream>>>((const unsigned short*)A_imag);
    pos_t_kernel<<<512, 256, 0, stream>>>(pos);
    proj_kernel<<<(D_MODEL * LSEQ) / 256, 256, 0, stream>>>(x, Wproj, bproj);
    prep_kernel<<<(NLAYERS * PN) / 256, 256, 0, stream>>>(
        log_dt, log_A_real, A_imag, C_re, C_im);
    pack_w_kernel<<<(NLAYERS * WN) / 256, 256, 0, stream>>>(Wout);
    gmat_kernel<<<NLAYERS * 512, 256, 0, stream>>>();

    for (int i = 0; i < NLAYERS; i++) {
        ssd_kernel<<<D_MODEL, 512, 0, stream>>>(Dskip, i);   // one block per h, 8 waves
        glu_mfma_kernel<<<2048, 256, 0, stream>>>(bout, i);
        ln_kernel<<<(BATCH * LSEQ) / 32, 256, 0, stream>>>(ln_g, ln_b, i);
    }

    mean_kernel<<<BATCH * D_MODEL, 256, 0, stream>>>();
    stats_kernel<<<(BATCH * D_MODEL) / 256, 256, 0, stream>>>(
        Wstats, bstats, (float*)d_out);
}

// Round 20
// 909.250 us; speedup vs baseline: 1.0759x; 1.0759x over previous
//
#include <hip/hip_runtime.h>
#include <hip/hip_bf16.h>
#include <hip/hip_fp16.h>
#include <cmath>

// Problem constants
#define BATCH   8
#define D_MODEL 512
#define N2      32
#define LSEQ    4096
#define NLAYERS 4
#define CIN     3
#define NBDL    (16777216u)   // BATCH*D_MODEL*LSEQ
#define PN      (D_MODEL * N2)            // params per layer
#define WN      (2 * D_MODEL * D_MODEL)   // weights per layer

typedef __attribute__((ext_vector_type(8))) short short8;   // 8 bf16 (4 VGPRs)
typedef __attribute__((ext_vector_type(4))) float floatx4;  // MFMA accum

// ---------------------------------------------------------------------------
// Static device scratch. Every buffer fully overwritten before read, each call.
// Per layer: ssd writes y (bf16) into g_yb -> glu reads y from g_yb (in-LDS
// transpose staging) and writes z (fp16) into g_yt -> ln reads z from g_yt.
// ---------------------------------------------------------------------------
__device__ float   g_h[NBDL];                                  // 64 MB h (B,D,L) fp32
__device__ __align__(16) __hip_bfloat16 g_yb[NBDL];            // 32 MB y bf16 (B,D,L)
__device__ __align__(16) __hip_bfloat16 g_yt[NBDL];            // 32 MB z fp16 (B,D,L)
__device__ __align__(16) __hip_bfloat16 g_wb[NLAYERS * WN];    // 8 MB W bf16, all layers
__device__ __align__(16) __hip_bfloat16 g_G[(size_t)NLAYERS * 512 * 6 * 4096]; // 96 MB SSD mats
__device__ __align__(16) float g_posT[D_MODEL * LSEQ];         // 8 MB pos^T fp32
__device__ float4  g_p[NLAYERS * PN];                          // SSM params, all layers
__device__ float   g_hm[BATCH * D_MODEL];                      // mean over L
__device__ int     g_flag;                                     // 1=fp32, 0=bf16, 2=fp16

__device__ __forceinline__ float bfbits2f(unsigned short u) {
    union { unsigned int i; float f; } x; x.i = ((unsigned int)u) << 16; return x.f;
}
__device__ __forceinline__ float halfbits2f(unsigned short u) {
    __half h; *(unsigned short*)&h = u; return __half2float(h);
}
__device__ __forceinline__ float ldin(const void* p, size_t i, int m) {
    if (m == 1) return ((const float*)p)[i];
    unsigned short u = ((const unsigned short*)p)[i];
    if (m == 0) return bfbits2f(u);
    return halfbits2f(u);
}
__device__ __forceinline__ unsigned int pk2(float a, float b) {
    __hip_bfloat16 ha = __float2bfloat16(a), hb = __float2bfloat16(b);
    unsigned short ua, ub;
    __builtin_memcpy(&ua, &ha, 2); __builtin_memcpy(&ub, &hb, 2);
    return (unsigned int)ua | ((unsigned int)ub << 16);
}
// split a pair of fp32 into packed bf16 hi-words and bf16 lo-residual words
__device__ __forceinline__ void split2(float a, float b, unsigned int& hp, unsigned int& lp) {
    __hip_bfloat16 ah = __float2bfloat16(a), bh = __float2bfloat16(b);
    unsigned short ua, ub;
    __builtin_memcpy(&ua, &ah, 2); __builtin_memcpy(&ub, &bh, 2);
    hp = (unsigned int)ua | ((unsigned int)ub << 16);
    lp = pk2(a - __bfloat162float(ah), b - __bfloat162float(bh));
}
__device__ __forceinline__ unsigned short bf16u(float a) {
    __hip_bfloat16 h = __float2bfloat16(a);
    unsigned short u; __builtin_memcpy(&u, &h, 2); return u;
}
// complex integer power by binary exponentiation (exact-ish fp32, e in [0,64])
__device__ __forceinline__ float2 cpow_(float br, float bi, int e) {
    float rr = 1.f, ri = 0.f;
    while (e) {
        if (e & 1) { float t = rr * br - ri * bi; ri = rr * bi + ri * br; rr = t; }
        float t = br * br - bi * bi; bi = 2.f * br * bi; br = t;
        e >>= 1;
    }
    return make_float2(rr, ri);
}

// Branchless erf-based exact GELU (A&S 7.1.26, |err| < 1.5e-7)
__device__ __forceinline__ float fast_gelu(float x) {
    float z = x * 0.70710678118654752f;
    float a = fabsf(z);
    float t = __builtin_amdgcn_rcpf(fmaf(0.3275911f, a, 1.0f));
    float p = t * fmaf(t, fmaf(t, fmaf(t, fmaf(t, 1.061405429f, -1.453152027f),
                                       1.421413741f), -0.284496736f), 0.254829592f);
    float e = __expf(-a * a);
    float er = fmaf(-p, e, 1.0f);            // erf(|z|)
    er = copysignf(er, z);
    float hx = 0.5f * x;
    return fmaf(hx, er, hx);
}

// ---------------------------------------------------------------------------
// 0) dtype probe on A_imag (= pi*arange(32) broadcast; elt[1]=pi, elt[3]=3pi)
// ---------------------------------------------------------------------------
__global__ void detect_kernel(const unsigned short* a) {
    if (threadIdx.x == 0) {
        unsigned short h1 = a[1], h3 = a[3];
        int f;
        if (h1 == 0x0000 && h3 == 0x4049) f = 1;   // fp32 layout
        else if (h1 == 0x4049)            f = 0;   // native bf16
        else if (h1 == 0x4248)            f = 2;   // native fp16
        else                              f = 1;
        g_flag = f;
    }
}

__global__ __launch_bounds__(256) void sentinel_kernel(float* out, float v) {
    out[blockIdx.x * 256 + threadIdx.x] = v;
}

// ---------------------------------------------------------------------------
// 0b) pos transpose: g_posT[o][l] = pos[l][o] (fp32 exact). 64x64 LDS tiles.
// ---------------------------------------------------------------------------
__global__ __launch_bounds__(256) void pos_t_kernel(const void* pos) {
    __shared__ float T[64][65];
    const int m = g_flag;
    int tid = threadIdx.x;
    int bid = blockIdx.x;                // 0..511 = ltile*8 + otile
    int l0 = (bid >> 3) * 64;
    int o0 = (bid & 7) * 64;
    int a  = tid & 63;
    int g4 = tid >> 6;                   // 0..3
#pragma unroll
    for (int p = 0; p < 16; p++) {
        int ll = g4 * 16 + p;
        T[a][ll] = ldin(pos, (size_t)(l0 + ll) * D_MODEL + o0 + a, m);  // lanes: o-fast (coalesced)
    }
    __syncthreads();
#pragma unroll
    for (int p = 0; p < 16; p++) {
        int oo = g4 * 16 + p;
        g_posT[(size_t)(o0 + oo) * LSEQ + l0 + a] = T[oo][a];           // lanes: l-fast (coalesced)
    }
}

// ---------------------------------------------------------------------------
// 1) Input projection v3 — thread per (o,l), b looped in registers.
// ---------------------------------------------------------------------------
__global__ __launch_bounds__(256) void proj_kernel(const void* x, const void* Wproj,
                                                   const void* bproj) {
    const int m = g_flag;
    unsigned idx = blockIdx.x * 256 + threadIdx.x;   // over D_MODEL*LSEQ
    int l = idx & (LSEQ - 1);
    int o = idx >> 12;                               // 0..511
    float acc0 = ldin(bproj, o, m) + g_posT[(size_t)o * LSEQ + l];
    float w0 = ldin(Wproj, o * CIN + 0, m);
    float w1 = ldin(Wproj, o * CIN + 1, m);
    float w2 = ldin(Wproj, o * CIN + 2, m);
#pragma unroll
    for (int b = 0; b < BATCH; b++) {
        float acc = acc0;
        acc = fmaf(w0, ldin(x, (size_t)(b * CIN + 0) * LSEQ + l, m), acc);
        acc = fmaf(w1, ldin(x, (size_t)(b * CIN + 1) * LSEQ + l, m), acc);
        acc = fmaf(w2, ldin(x, (size_t)(b * CIN + 2) * LSEQ + l, m), acc);
        g_h[(size_t)(b * D_MODEL + o) * LSEQ + l] = acc;
    }
}

// ---------------------------------------------------------------------------
// 2) SSM param prep — ALL layers in one launch.
// ---------------------------------------------------------------------------
__global__ __launch_bounds__(256) void prep_kernel(const void* log_dt, const void* log_A_real,
                                                   const void* A_imag, const void* C_re,
                                                   const void* C_im) {
    const int m = g_flag;
    int idx = blockIdx.x * 256 + threadIdx.x;        // over NLAYERS*PN
    int layer = idx >> 14;                           // PN = 16384
    int i = idx & (PN - 1);
    int hh = i >> 5;
    size_t oH = (size_t)layer * D_MODEL;
    size_t oN = (size_t)layer * PN;
    float dt  = expf(ldin(log_dt, oH + hh, m));
    float a   = expf(ldin(log_A_real, oN + i, m));
    float bi  = ldin(A_imag, oN + i, m);
    float dre = -a * dt, dim = bi * dt;
    float er  = expf(dre);
    float wr  = er * cosf(dim);
    float wi  = er * sinf(dim);
    float Er  = wr - 1.0f, Ei = wi;
    float inv = 1.0f / (a * a + bi * bi);
    float Tr = (-Er * a + Ei * bi) * inv;
    float Ti = -(Er * bi + Ei * a) * inv;
    float cr = ldin(C_re, oN + i, m), ci = ldin(C_im, oN + i, m);
    float c2r = 2.0f * (cr * Tr - ci * Ti);
    float c2i = 2.0f * (cr * Ti + ci * Tr);
    g_p[idx] = make_float4(wr, wi, c2r, c2i);
}

// ---------------------------------------------------------------------------
// 2b) Pack Wout to bf16 — ALL layers in one launch.
// ---------------------------------------------------------------------------
__global__ __launch_bounds__(256) void pack_w_kernel(const void* Wout) {
    int idx = blockIdx.x * 256 + threadIdx.x;        // over NLAYERS*WN
    g_wb[idx] = __float2bfloat16(ldin(Wout, idx, g_flag));
}

// ---------------------------------------------------------------------------
// 2c) SSD matrix precompute v2 — geometric stepping.
// ---------------------------------------------------------------------------
__global__ __launch_bounds__(256) void gmat_kernel() {
    __shared__ float4 psh[32];
    __shared__ unsigned short Khi[64], Klo[64];
    __shared__ __align__(16) unsigned short sC[2][64][72];   // 18.4 KB C staging
    float (*Kpart)[64] = (float(*)[64])&sC[0][0][0];         // 8 KB alias (pre-C)
    int tid = threadIdx.x;
    int bid = blockIdx.x;                   // layer*512 + h
    int layer = bid >> 9, h = bid & 511;
    if (tid < 32) psh[tid] = g_p[(size_t)layer * PN + h * N2 + tid];
    __syncthreads();
    // K partials: thread (n, dseg), tid<128: w^d stepped along d
    if (tid < 128) {
        int n = tid >> 2, dseg = (tid & 3) * 16;
        float4 pv = psh[n];
        float wr = pv.x, wi = pv.y;
        float2 wd = cpow_(wr, wi, dseg);
#pragma unroll
        for (int i = 0; i < 16; i++) {
            Kpart[n][dseg + i] = pv.z * wd.x - pv.w * wd.y;
            float t2 = wd.x * wr - wd.y * wi;
            wd.y = wd.x * wi + wd.y * wr; wd.x = t2;
        }
    }
    __syncthreads();
    if (tid < 64) {
        float acc = 0.f;
#pragma unroll
        for (int n = 0; n < 32; n++) acc += Kpart[n][tid];
        unsigned short khu = bf16u(acc);
        Khi[tid] = khu;
        Klo[tid] = bf16u(acc - bfbits2f(khu));
    }
    __syncthreads();                        // Kpart dead; sC reusable below
    unsigned short* Gu = (unsigned short*)(g_G + (size_t)bid * 6 * 4096);
    int t = tid >> 2, jseg = (tid & 3) * 16;
    // ---- M rows (gather from Khi/Klo, coalesced 16B stores) ----
    {
        unsigned int mh[8], ml[8];
#pragma unroll
        for (int i2 = 0; i2 < 8; i2++) {
            int d0 = t - jseg - 2 * i2;
            int d1 = d0 - 1;
            unsigned int h0 = (d0 >= 0) ? (unsigned int)Khi[d0] : 0u;
            unsigned int h1 = (d1 >= 0) ? (unsigned int)Khi[d1] : 0u;
            unsigned int l0v = (d0 >= 0) ? (unsigned int)Klo[d0] : 0u;
            unsigned int l1v = (d1 >= 0) ? (unsigned int)Klo[d1] : 0u;
            mh[i2] = h0 | (h1 << 16);
            ml[i2] = l0v | (l1v << 16);
        }
        uint4 v;
        v.x = mh[0]; v.y = mh[1]; v.z = mh[2]; v.w = mh[3];
        *(uint4*)&Gu[t * 64 + jseg] = v;
        v.x = mh[4]; v.y = mh[5]; v.z = mh[6]; v.w = mh[7];
        *(uint4*)&Gu[t * 64 + jseg + 8] = v;
        v.x = ml[0]; v.y = ml[1]; v.z = ml[2]; v.w = ml[3];
        *(uint4*)&Gu[4096 + t * 64 + jseg] = v;
        v.x = ml[4]; v.y = ml[5]; v.z = ml[6]; v.w = ml[7];
        *(uint4*)&Gu[4096 + t * 64 + jseg + 8] = v;
    }
    // ---- A rows: w^{63-j}, stepped ascending e = descending j ----
    {
        int n = t >> 1;
        float4 pv = psh[n];
        float wr = pv.x, wi = pv.y;
        float av[16];
        float2 wd = cpow_(wr, wi, 48 - jseg);           // e for col jseg+15
#pragma unroll
        for (int i = 15; i >= 0; i--) {
            av[i] = (t & 1) ? wd.y : wd.x;
            float t2 = wd.x * wr - wd.y * wi;
            wd.y = wd.x * wi + wd.y * wr; wd.x = t2;
        }
        unsigned int ah[8], al[8];
#pragma unroll
        for (int i2 = 0; i2 < 8; i2++)
            split2(av[2 * i2], av[2 * i2 + 1], ah[i2], al[i2]);
        uint4 v;
        v.x = ah[0]; v.y = ah[1]; v.z = ah[2]; v.w = ah[3];
        *(uint4*)&Gu[2 * 4096 + t * 64 + jseg] = v;
        v.x = ah[4]; v.y = ah[5]; v.z = ah[6]; v.w = ah[7];
        *(uint4*)&Gu[2 * 4096 + t * 64 + jseg + 8] = v;
        v.x = al[0]; v.y = al[1]; v.z = al[2]; v.w = al[3];
        *(uint4*)&Gu[3 * 4096 + t * 64 + jseg] = v;
        v.x = al[4]; v.y = al[5]; v.z = al[6]; v.w = al[7];
        *(uint4*)&Gu[3 * 4096 + t * 64 + jseg + 8] = v;
    }
    // ---- C cols: c2*w^{t+1}, stepped along t; stage in LDS ----
    {
        int j = tid >> 2, tseg = (tid & 3) * 16;
        int n = j >> 1;
        float4 pv = psh[n];
        float wr = pv.x, wi = pv.y;
        float2 wd = cpow_(wr, wi, tseg + 1);
#pragma unroll
        for (int i = 0; i < 16; i++) {
            float zr = pv.z * wd.x - pv.w * wd.y;
            float zi = pv.z * wd.y + pv.w * wd.x;
            float cv = (j & 1) ? -zi : zr;
            unsigned short chu = bf16u(cv);
            sC[0][tseg + i][j] = chu;
            sC[1][tseg + i][j] = bf16u(cv - bfbits2f(chu));
            float t2 = wd.x * wr - wd.y * wi;
            wd.y = wd.x * wi + wd.y * wr; wd.x = t2;
        }
    }
    __syncthreads();
    // coalesced copy out of the C staging
    *(uint4*)&Gu[4 * 4096 + t * 64 + jseg]     = *(uint4*)&sC[0][t][jseg];
    *(uint4*)&Gu[4 * 4096 + t * 64 + jseg + 8] = *(uint4*)&sC[0][t][jseg + 8];
    *(uint4*)&Gu[5 * 4096 + t * 64 + jseg]     = *(uint4*)&sC[1][t][jseg];
    *(uint4*)&Gu[5 * 4096 + t * 64 + jseg + 8] = *(uint4*)&sC[1][t][jseg + 8];
}

// ---------------------------------------------------------------------------
// 3) SSD kernel v4 (proven at 961 us): one block per h (256 thr), b looped;
//    M staged once; A/C restaged per b (L2-hot). T14 async u-staging.
// ---------------------------------------------------------------------------
__global__ __launch_bounds__(256) void ssd_kernel(const void* Dskip, int layer) {
    __shared__ unsigned short sMhi[64][72];   // 9216 B each, 144 B row stride
    __shared__ unsigned short sMlo[64][72];
    __shared__ unsigned short sAC[64][72];    // A (hi then lo), later C (hi then lo)
    __shared__ unsigned short sUhi[64][72];
    __shared__ unsigned short sUlo[64][72];
    __shared__ float sPf[64][68];             // P fp32; later S hi/lo bf16 (17408 B)
    const int m = g_flag;
    int tid = threadIdx.x;
    int h = blockIdx.x;                       // 0..511
    const unsigned short* Gsrc = (const unsigned short*)g_G + (size_t)(layer * 512 + h) * 6 * 4096;

    int row = tid >> 2, seg = (tid & 3) * 16;

    // prologue: M hi/lo (once) + Ahi + u(b=0)
    {
        const unsigned short* s = Gsrc + row * 64 + seg;
        *(uint4*)&sMhi[row][seg]     = *(const uint4*)(s);
        *(uint4*)&sMhi[row][seg + 8] = *(const uint4*)(s + 8);
        *(uint4*)&sMlo[row][seg]     = *(const uint4*)(s + 4096);
        *(uint4*)&sMlo[row][seg + 8] = *(const uint4*)(s + 4096 + 8);
        *(uint4*)&sAC[row][seg]      = *(const uint4*)(s + 2 * 4096);
        *(uint4*)&sAC[row][seg + 8]  = *(const uint4*)(s + 2 * 4096 + 8);
    }
    {
        const float* up = g_h + (size_t)h * LSEQ + row * 64 + seg;   // b = 0
#pragma unroll
        for (int s8 = 0; s8 < 2; s8++) {
            float4 va = *(const float4*)(up + s8 * 8);
            float4 vb = *(const float4*)(up + s8 * 8 + 4);
            uint4 H, L;
            split2(va.x, va.y, H.x, L.x);
            split2(va.z, va.w, H.y, L.y);
            split2(vb.x, vb.y, H.z, L.z);
            split2(vb.z, vb.w, H.w, L.w);
            *(uint4*)&sUhi[row][seg + s8 * 8] = H;
            *(uint4*)&sUlo[row][seg + s8 * 8] = L;
        }
    }

    // hoisted scan constants (wave0 lanes) + dsk (all threads)
    float sWr = 0.f, sWi = 0.f;
    if (tid < 32) {
        float4 pv = g_p[(size_t)layer * PN + h * N2 + tid];
        float Wr = pv.x, Wi = pv.y;
#pragma unroll
        for (int s6 = 0; s6 < 6; s6++) { float t2 = Wr * Wr - Wi * Wi; Wi = 2.f * Wr * Wi; Wr = t2; }
        sWr = Wr; sWi = Wi;
    }
    float dsk = ldin(Dskip, (size_t)layer * D_MODEL + h, m);

    int lane = tid & 63, wave = tid >> 6;
    int q = lane >> 4, nm = lane & 15;
    int cidx = wave * 16 + nm;                                  // this lane's col (chunk)
    floatx4 zed = {0.f, 0.f, 0.f, 0.f};

    for (int b = 0; b < 8; b++) {
        __syncthreads();                                        // B1 (staging visible)
        // T14: issue u(b+1) loads EARLY into regs; latency hides under b's work
        float4 nu0, nu1, nu2, nu3;
        if (b < 7) {
            const float* up = g_h + (size_t)((b + 1) * D_MODEL + h) * LSEQ + row * 64 + seg;
            nu0 = *(const float4*)(up);
            nu1 = *(const float4*)(up + 4);
            nu2 = *(const float4*)(up + 8);
            nu3 = *(const float4*)(up + 12);
        }
        floatx4 pacc[4] = {zed, zed, zed, zed};
        // GEMM2a: P += Ahi@(Uhi + Ulo)
#pragma unroll
        for (int k0 = 0; k0 < 64; k0 += 32) {
            short8 bh = *(short8*)&sUhi[cidx][k0 + q * 8];
            short8 bl = *(short8*)&sUlo[cidx][k0 + q * 8];
#pragma unroll
            for (int mi = 0; mi < 4; mi++) {
                short8 a = *(short8*)&sAC[mi * 16 + nm][k0 + q * 8];
                pacc[mi] = __builtin_amdgcn_mfma_f32_16x16x32_bf16(a, bh, pacc[mi], 0, 0, 0);
                pacc[mi] = __builtin_amdgcn_mfma_f32_16x16x32_bf16(a, bl, pacc[mi], 0, 0, 0);
            }
        }
        __syncthreads();                                        // B2 (Ahi reads done)
        if (tid >= 128) {   // L2: Alo
            int idx = tid - 128, row2 = idx >> 1, seg2 = (idx & 1) * 32;
            const unsigned short* s = Gsrc + 3 * 4096 + row2 * 64 + seg2;
            *(uint4*)&sAC[row2][seg2]      = *(const uint4*)(s);
            *(uint4*)&sAC[row2][seg2 + 8]  = *(const uint4*)(s + 8);
            *(uint4*)&sAC[row2][seg2 + 16] = *(const uint4*)(s + 16);
            *(uint4*)&sAC[row2][seg2 + 24] = *(const uint4*)(s + 24);
        }
        __syncthreads();                                        // B3
        // GEMM2b: P += Alo@Uhi; store P ([col][row]) to LDS fp32
#pragma unroll
        for (int k0 = 0; k0 < 64; k0 += 32) {
            short8 bh = *(short8*)&sUhi[cidx][k0 + q * 8];
#pragma unroll
            for (int mi = 0; mi < 4; mi++) {
                short8 a = *(short8*)&sAC[mi * 16 + nm][k0 + q * 8];
                pacc[mi] = __builtin_amdgcn_mfma_f32_16x16x32_bf16(a, bh, pacc[mi], 0, 0, 0);
            }
        }
#pragma unroll
        for (int mi = 0; mi < 4; mi++)
            *(floatx4*)&sPf[cidx][mi * 16 + q * 4] = pacc[mi];
        __syncthreads();                                        // B4 (P visible)

        // inter-chunk scan (wave0 lanes 0..31), in-place S over P
        if (tid < 32) {
            int n = tid;
            float Sr = 0.f, Si = 0.f;
            for (int c = 0; c < 64; c++) {
                unsigned int* wp = (unsigned int*)&sPf[c][0];
                unsigned int pru = wp[2 * n], piu = wp[2 * n + 1];   // read P BEFORE S write
                float pr = __uint_as_float(pru), pi = __uint_as_float(piu);
                unsigned int shw, slw;
                split2(Sr, Si, shw, slw);
                wp[n]      = shw;                                    // Shi ushorts [0..63]
                wp[32 + n] = slw;                                    // Slo ushorts [64..127]
                float t2 = fmaf(sWr, Sr, fmaf(-sWi, Si, pr));
                Si = fmaf(sWr, Si, fmaf(sWi, Sr, pi));
                Sr = t2;
            }
        }
        if (tid >= 128) {   // L3: Chi (concurrent with scan; A dead after B4)
            int idx = tid - 128, row2 = idx >> 1, seg2 = (idx & 1) * 32;
            const unsigned short* s = Gsrc + 4 * 4096 + row2 * 64 + seg2;
            *(uint4*)&sAC[row2][seg2]      = *(const uint4*)(s);
            *(uint4*)&sAC[row2][seg2 + 8]  = *(const uint4*)(s + 8);
            *(uint4*)&sAC[row2][seg2 + 16] = *(const uint4*)(s + 16);
            *(uint4*)&sAC[row2][seg2 + 24] = *(const uint4*)(s + 24);
        }
        __syncthreads();                                        // B5 (S + Chi ready)

        // GEMM1: Yintra = (Mhi+Mlo)@(Uhi+Ulo); GEMM3a: Ycarry = Chi@(Shi+Slo)
        floatx4 accA[4] = {zed, zed, zed, zed};
        floatx4 accB[4] = {zed, zed, zed, zed};
#pragma unroll
        for (int k0 = 0; k0 < 64; k0 += 32) {
            short8 bh = *(short8*)&sUhi[cidx][k0 + q * 8];
            short8 bl = *(short8*)&sUlo[cidx][k0 + q * 8];
            const unsigned short* srow = (const unsigned short*)&sPf[cidx][0];
            short8 sh = *(short8*)(srow + k0 + q * 8);
            short8 sl = *(short8*)(srow + 64 + k0 + q * 8);
#pragma unroll
            for (int mi = 0; mi < 4; mi++) {
                short8 amh = *(short8*)&sMhi[mi * 16 + nm][k0 + q * 8];
                short8 aml = *(short8*)&sMlo[mi * 16 + nm][k0 + q * 8];
                short8 ac  = *(short8*)&sAC [mi * 16 + nm][k0 + q * 8];
                accA[mi] = __builtin_amdgcn_mfma_f32_16x16x32_bf16(amh, bh, accA[mi], 0, 0, 0);
                accA[mi] = __builtin_amdgcn_mfma_f32_16x16x32_bf16(amh, bl, accA[mi], 0, 0, 0);
                accA[mi] = __builtin_amdgcn_mfma_f32_16x16x32_bf16(aml, bh, accA[mi], 0, 0, 0);
                accB[mi] = __builtin_amdgcn_mfma_f32_16x16x32_bf16(ac,  sh, accB[mi], 0, 0, 0);
                accB[mi] = __builtin_amdgcn_mfma_f32_16x16x32_bf16(ac,  sl, accB[mi], 0, 0, 0);
            }
        }
        __syncthreads();                                        // B6 (Chi reads done)
        if (tid >= 128) {   // L4: Clo
            int idx = tid - 128, row2 = idx >> 1, seg2 = (idx & 1) * 32;
            const unsigned short* s = Gsrc + 5 * 4096 + row2 * 64 + seg2;
            *(uint4*)&sAC[row2][seg2]      = *(const uint4*)(s);
            *(uint4*)&sAC[row2][seg2 + 8]  = *(const uint4*)(s + 8);
            *(uint4*)&sAC[row2][seg2 + 16] = *(const uint4*)(s + 16);
            *(uint4*)&sAC[row2][seg2 + 24] = *(const uint4*)(s + 24);
        }
        __syncthreads();                                        // B7
        // GEMM3b: Ycarry += Clo@Shi
#pragma unroll
        for (int k0 = 0; k0 < 64; k0 += 32) {
            const unsigned short* srow = (const unsigned short*)&sPf[cidx][0];
            short8 sh = *(short8*)(srow + k0 + q * 8);
#pragma unroll
            for (int mi = 0; mi < 4; mi++) {
                short8 ac = *(short8*)&sAC[mi * 16 + nm][k0 + q * 8];
                accB[mi] = __builtin_amdgcn_mfma_f32_16x16x32_bf16(ac, sh, accB[mi], 0, 0, 0);
            }
        }

        // epilogue: y = Yintra + Ycarry + dsk*u -> gelu -> bf16 store
        __hip_bfloat16* yb = g_yb + (size_t)(b * D_MODEL + h) * LSEQ;
#pragma unroll
        for (int mi = 0; mi < 4; mi++) {
            int t0 = mi * 16 + q * 4;
            uint2 uh = *(uint2*)&sUhi[cidx][t0];
            uint2 ul = *(uint2*)&sUlo[cidx][t0];
            float u0 = bfbits2f((unsigned short)(uh.x & 0xFFFF)) + bfbits2f((unsigned short)(ul.x & 0xFFFF));
            float u1 = bfbits2f((unsigned short)(uh.x >> 16))    + bfbits2f((unsigned short)(ul.x >> 16));
            float u2 = bfbits2f((unsigned short)(uh.y & 0xFFFF)) + bfbits2f((unsigned short)(ul.y & 0xFFFF));
            float u3 = bfbits2f((unsigned short)(uh.y >> 16))    + bfbits2f((unsigned short)(ul.y >> 16));
            float y0 = fast_gelu(accA[mi][0] + accB[mi][0] + dsk * u0);
            float y1 = fast_gelu(accA[mi][1] + accB[mi][1] + dsk * u1);
            float y2 = fast_gelu(accA[mi][2] + accB[mi][2] + dsk * u2);
            float y3 = fast_gelu(accA[mi][3] + accB[mi][3] + dsk * u3);
            uint2 o;
            o.x = pk2(y0, y1);
            o.y = pk2(y2, y3);
            *(uint2*)&yb[cidx * 64 + t0] = o;
        }
        __syncthreads();                                        // B8 (sAC/sU reads done)
        if (b < 7) {
            // restage Ahi (L2-hot) + u(b+1) from the early-issued regs
            {
                const unsigned short* s = Gsrc + 2 * 4096 + row * 64 + seg;
                *(uint4*)&sAC[row][seg]     = *(const uint4*)(s);
                *(uint4*)&sAC[row][seg + 8] = *(const uint4*)(s + 8);
            }
            {
                uint4 H, L;
                split2(nu0.x, nu0.y, H.x, L.x);
                split2(nu0.z, nu0.w, H.y, L.y);
                split2(nu1.x, nu1.y, H.z, L.z);
                split2(nu1.z, nu1.w, H.w, L.w);
                *(uint4*)&sUhi[row][seg] = H;
                *(uint4*)&sUlo[row][seg] = L;
                split2(nu2.x, nu2.y, H.x, L.x);
                split2(nu2.z, nu2.w, H.y, L.y);
                split2(nu3.x, nu3.y, H.z, L.z);
                split2(nu3.z, nu3.w, H.w, L.w);
                *(uint4*)&sUhi[row][seg + 8] = H;
                *(uint4*)&sUlo[row][seg + 8] = L;
            }
        }
    }
}

// ---------------------------------------------------------------------------
// 4) MFMA GLU v7: v4 + physical row permutation phi(r) = r ^ (((r>>6)&3)<<1)
//    on the Ytd tile (staging write conflicts 4-way -> 2-way = free).
// ---------------------------------------------------------------------------
__global__ __launch_bounds__(256, 4) void glu_mfma_kernel(const void* bout, int layer) {
    __shared__ __align__(16) unsigned char smem[25600];
    unsigned short (* __restrict__ Wa)[40] = (unsigned short(*)[40])(smem);          // 2560 B
    unsigned short (* __restrict__ Wb)[40] = (unsigned short(*)[40])(smem + 2560);   // 2560 B
    unsigned int*  __restrict__ Ytd        = (unsigned int*)(smem + 5120);           // 256 rows x 20 dwords = 20480 B
    unsigned short (* __restrict__ Zs)[264] = (unsigned short(*)[264])(smem);        // 16896 B (aliases, post-loop)
    const int m = g_flag;
    int tid  = threadIdx.x;
    int wave = tid >> 6, lane = tid & 63;
    int q = lane >> 4, nm = lane & 15;
    int bid = blockIdx.x;                    // 0..2047
    int xcd = bid & 7;
    int qb  = bid >> 3;                      // 0..255
    int rt  = qb & 15;                       // 0..15  (32 o-rows) fast within XCD
    int ct  = (xcd << 4) | (qb >> 4);        // 0..127 (256 l-cols) 16 per XCD
    int col0 = ct * 256;
    int row0 = rt * 32;
    int b  = col0 >> 12;                     // single batch per block
    int l0 = col0 & (LSEQ - 1);
    const unsigned short* __restrict__ Ybb =
        (const unsigned short*)g_yb + (size_t)b * D_MODEL * LSEQ;
    const __hip_bfloat16* __restrict__ Wbase = g_wb + (size_t)layer * WN;

    floatx4 accA[2][4], accB[2][4];
    floatx4 zed = {0.f, 0.f, 0.f, 0.f};
#pragma unroll
    for (int i = 0; i < 2; i++)
#pragma unroll
        for (int j = 0; j < 4; j++) { accA[i][j] = zed; accB[i][j] = zed; }

    int sk = (tid & 3) * 8;         // 0,8,16,24 (W staging col)
    int wrow = (tid & 127) >> 2;    // 0..31 (W staging row)
    int p  = tid >> 4;              // 0..15 k-pair for y staging
    int sg = tid & 15;              // 0..15 l-segment (16 l each)
    int Xw = (sg & 3) << 2;         // write swizzle (dwords)
    int xorv = (sg >> 2) << 1;      // row permutation phi: bits 1-2 of row idx
    unsigned int rowbase = (unsigned)(sg * 16) * 20 + (unsigned)(p ^ Xw);
    int wavecol = wave * 64;

    for (int k0 = 0; k0 < D_MODEL; k0 += 32) {
        if (tid < 128)
            *(uint4*)&Wa[wrow][sk] = *(const uint4*)&Wbase[(size_t)(row0 + wrow) * D_MODEL + k0 + sk];
        else
            *(uint4*)&Wb[wrow][sk] = *(const uint4*)&Wbase[(size_t)(row0 + wrow + D_MODEL) * D_MODEL + k0 + sk];
        // y staging with in-LDS transpose: rows k0+2p, k0+2p+1, l-seg sg*16..+15
        // phi row permutation: value for local row jj stored at row (jj ^ xorv)
        {
            const unsigned short* yA = Ybb + (size_t)(k0 + 2 * p) * LSEQ + l0 + sg * 16;
            uint4 a0 = *(const uint4*)yA;
            uint4 a1 = *(const uint4*)(yA + 8);
            uint4 b0 = *(const uint4*)(yA + LSEQ);
            uint4 b1 = *(const uint4*)(yA + LSEQ + 8);
#define PKW(au, bu, jj)  { \
            Ytd[rowbase + ((jj) ^ xorv) * 20]       = ((au) & 0xFFFFu) | ((bu) << 16); \
            Ytd[rowbase + (((jj) + 1) ^ xorv) * 20] = ((au) >> 16) | ((bu) & 0xFFFF0000u); }
            PKW(a0.x, b0.x, 0)  PKW(a0.y, b0.y, 2)  PKW(a0.z, b0.z, 4)  PKW(a0.w, b0.w, 6)
            PKW(a1.x, b1.x, 8)  PKW(a1.y, b1.y, 10) PKW(a1.z, b1.z, 12) PKW(a1.w, b1.w, 14)
#undef PKW
        }
        __syncthreads();
        short8 afa[2], afb[2];
#pragma unroll
        for (int mi = 0; mi < 2; mi++) {
            afa[mi] = *(short8*)&Wa[mi * 16 + nm][q * 8];
            afb[mi] = *(short8*)&Wb[mi * 16 + nm][q * 8];
        }
#pragma unroll
        for (int ni = 0; ni < 4; ni++) {
            int r = wavecol + ni * 16 + nm;
            int pr = r ^ (((r >> 6) & 3) << 1);      // phi (uniform shift within wave)
            int Xr = ((r >> 4) & 3) << 2;
            short8 bf = *(short8*)(Ytd + pr * 20 + ((q * 4) ^ Xr));
#pragma unroll
            for (int mi = 0; mi < 2; mi++) {
                accA[mi][ni] = __builtin_amdgcn_mfma_f32_16x16x32_bf16(afa[mi], bf, accA[mi][ni], 0, 0, 0);
                accB[mi][ni] = __builtin_amdgcn_mfma_f32_16x16x32_bf16(afb[mi], bf, accB[mi][ni], 0, 0, 0);
            }
        }
        __syncthreads();
    }

    // epilogue: z -> LDS repack (fp16), then coalesced global stores to g_yt
    size_t boff = (size_t)layer * 2 * D_MODEL;
#pragma unroll
    for (int mi = 0; mi < 2; mi++) {
#pragma unroll
        for (int r = 0; r < 4; r++) {
            int lrow = mi * 16 + q * 4 + r;          // 0..31
            int o = row0 + lrow;
            float ba  = ldin(bout, boff + o, m);
            float bb2 = ldin(bout, boff + o + D_MODEL, m);
#pragma unroll
            for (int ni = 0; ni < 4; ni++) {
                int lcol = wavecol + ni * 16 + nm;
                float aa = accA[mi][ni][r] + ba;
                float bv = accB[mi][ni][r] + bb2;
                float z  = aa * __builtin_amdgcn_rcpf(1.0f + __expf(-bv));
                __half hz = __float2half(z);
                unsigned short hzb;
                __builtin_memcpy(&hzb, &hz, 2);
                Zs[lrow][lcol] = hzb;
            }
        }
    }
    __syncthreads();
    unsigned short* __restrict__ Zb =
        (unsigned short*)g_yt + (size_t)b * D_MODEL * LSEQ;
    int zrow = tid >> 3;             // 0..31
    int zcol = (tid & 7) * 32;       // 0..224 (shorts)
    size_t gbase = (size_t)(row0 + zrow) * LSEQ + l0 + zcol;
#pragma unroll
    for (int i = 0; i < 4; i++)
        *(uint4*)&Zb[gbase + i * 8] = *(uint4*)&Zs[zrow][zcol + i * 8];
}

// ---------------------------------------------------------------------------
// 5) LayerNorm v2: 512 threads, 64-wide l-tiles -> every global access is a
//    256 B contiguous wave segment (was 2 x 128 B split). Per-thread d-range
//    and reduce order identical to v1 -> bit-identical arithmetic.
// ---------------------------------------------------------------------------
__global__ __launch_bounds__(512) void ln_kernel(const void* g, const void* bt, int layer) {
    __shared__ float s_sum[8][64];
    __shared__ float s_sq[8][64];
    __shared__ float s_mu[64], s_rs[64];
    const int m = g_flag;
    int tid = threadIdx.x;
    int l  = tid & 63;
    int dg = tid >> 6;                   // 0..7 -> d range [dg*64, dg*64+64)
    int bl = blockIdx.x;                 // 0..511 = b*64 + ltile
    int b  = bl >> 6;
    int l0 = (bl & 63) * 64;
    size_t base = (size_t)b * D_MODEL * LSEQ + l0 + l;
    float* __restrict__ hp = g_h + base + (size_t)(dg * 64) * LSEQ;
    const unsigned short* __restrict__ zp =
        (const unsigned short*)g_yt + base + (size_t)(dg * 64) * LSEQ;
    size_t goff = (size_t)layer * D_MODEL + dg * 64;
    float varr[64];
    float sum = 0.f, sq = 0.f;
#pragma unroll
    for (int i = 0; i < 64; i++) {
        float v = hp[(size_t)i * LSEQ] + halfbits2f(zp[(size_t)i * LSEQ]);
        varr[i] = v;
        sum += v; sq += v * v;
    }
    s_sum[dg][l] = sum; s_sq[dg][l] = sq;
    __syncthreads();
    if (tid < 64) {
        float s = 0.f, qq = 0.f;
#pragma unroll
        for (int gq = 0; gq < 8; gq++) { s += s_sum[gq][tid]; qq += s_sq[gq][tid]; }
        float mu = s * (1.0f / D_MODEL);
        float var = qq * (1.0f / D_MODEL) - mu * mu;
        s_mu[tid] = mu;
        s_rs[tid] = rsqrtf(var + 1e-5f);
    }
    __syncthreads();
    float mu = s_mu[l], rs = s_rs[l];
#pragma unroll
    for (int i = 0; i < 64; i++) {
        hp[(size_t)i * LSEQ] = (varr[i] - mu) * rs * ldin(g, goff + i, m) + ldin(bt, goff + i, m);
    }
}

// ---------------------------------------------------------------------------
// 6) Mean over L: one block per (b,d)
// ---------------------------------------------------------------------------
__global__ __launch_bounds__(256) void mean_kernel() {
    int bd = blockIdx.x;
    int tid = threadIdx.x;
    const float* __restrict__ row = g_h + (size_t)bd * LSEQ;
    float s = 0.f;
    for (int l = tid; l < LSEQ; l += 256) s += row[l];
#pragma unroll
    for (int off = 32; off > 0; off >>= 1) s += __shfl_down(s, off, 64);
    __shared__ float red[4];
    if ((tid & 63) == 0) red[tid >> 6] = s;
    __syncthreads();
    if (tid == 0) g_hm[bd] = (red[0] + red[1] + red[2] + red[3]) * (1.0f / LSEQ);
}

// ---------------------------------------------------------------------------
// 7) Final stats head -> FP32 output (mu flat || log_sig flat)
// ---------------------------------------------------------------------------
__global__ __launch_bounds__(256) void stats_kernel(const void* Wst, const void* bst,
                                                    float* __restrict__ out) {
    const int m = g_flag;
    int idx = blockIdx.x * 256 + threadIdx.x;
    int b = idx >> 9, o = idx & (D_MODEL - 1);
    const float* __restrict__ hb = g_hm + b * D_MODEL;
    float acc = ldin(bst, o, m);
    for (int d = 0; d < D_MODEL; d++)
        acc = fmaf(hb[d], ldin(Wst, (size_t)o * D_MODEL + d, m), acc);
    int pos = (o < 256) ? (b * 256 + o) : (2048 + b * 256 + (o - 256));
    out[pos] = acc;
}

// ---------------------------------------------------------------------------
extern "C" void kernel_launch(void* const* d_in, const int* in_sizes, int n_in,
                              void* d_out, int out_size, void* d_ws, size_t ws_size,
                              hipStream_t stream) {
    static const int exp_sizes[16] = {98304, 1536, 512, 2097152, 2048, 65536, 65536,
                                      65536, 65536, 2048, 2097152, 4096, 2048, 2048,
                                      262144, 512};
    bool ok = (n_in == 16);
    if (ok) for (int i = 0; i < 16; i++) if (in_sizes[i] != exp_sizes[i]) { ok = false; break; }
    if (!ok) {
        sentinel_kernel<<<(out_size + 255) / 256, 256, 0, stream>>>((float*)d_out, 1000.0f);
        return;
    }
    if (out_size != 4096) {
        sentinel_kernel<<<(out_size + 255) / 256, 256, 0, stream>>>((float*)d_out, 300.0f);
        return;
    }

    const void* x          = d_in[0];
    const void* Wproj      = d_in[1];
    const void* bproj      = d_in[2];
    const void* pos        = d_in[3];
    const void* log_dt     = d_in[4];
    const void* log_A_real = d_in[5];
    const void* A_imag     = d_in[6];
    const void* C_re       = d_in[7];
    const void* C_im       = d_in[8];
    const void* Dskip      = d_in[9];
    const void* Wout       = d_in[10];
    const void* bout       = d_in[11];
    const void* ln_g       = d_in[12];
    const void* ln_b       = d_in[13];
    const void* Wstats     = d_in[14];
    const void* bstats     = d_in[15];

    detect_kernel<<<1, 64, 0, stream>>>((const unsigned short*)A_imag);
    pos_t_kernel<<<512, 256, 0, stream>>>(pos);
    proj_kernel<<<(D_MODEL * LSEQ) / 256, 256, 0, stream>>>(x, Wproj, bproj);
    prep_kernel<<<(NLAYERS * PN) / 256, 256, 0, stream>>>(
        log_dt, log_A_real, A_imag, C_re, C_im);
    pack_w_kernel<<<(NLAYERS * WN) / 256, 256, 0, stream>>>(Wout);
    gmat_kernel<<<NLAYERS * 512, 256, 0, stream>>>();

    for (int i = 0; i < NLAYERS; i++) {
        ssd_kernel<<<D_MODEL, 256, 0, stream>>>(Dskip, i);   // one block per h, b looped
        glu_mfma_kernel<<<2048, 256, 0, stream>>>(bout, i);
        ln_kernel<<<(BATCH * LSEQ) / 64, 512, 0, stream>>>(ln_g, ln_b, i);
    }

    mean_kernel<<<BATCH * D_MODEL, 256, 0, stream>>>();
    stats_kernel<<<(BATCH * D_MODEL) / 256, 256, 0, stream>>>(
        Wstats, bstats, (float*)d_out);
}